// Round 1
// baseline (9071.716 us; speedup 1.0000x reference)
//
#include <hip/hip_runtime.h>
#include <hip/hip_cooperative_groups.h>

namespace cg = cooperative_groups;

typedef __attribute__((ext_vector_type(8))) short short8;
typedef __attribute__((ext_vector_type(4))) float floatx4;

#define GLOBAL_AS __attribute__((address_space(1)))
#define LDS_AS    __attribute__((address_space(3)))

__device__ __forceinline__ float bf2f(unsigned short u) {
  union { float f; unsigned int i; } v; v.i = ((unsigned int)u) << 16; return v.f;
}
__device__ __forceinline__ unsigned short f2bf(float f) {
  union { float f; unsigned int i; } v; v.f = f;
  unsigned int r = (v.i + 0x7fffu + ((v.i >> 16) & 1u)) >> 16;
  return (unsigned short)r;
}
__device__ __forceinline__ float sigm(float x) { return 1.0f / (1.0f + __expf(-x)); }
__device__ __forceinline__ float tanh_f(float x) { return 2.0f * sigm(2.0f * x) - 1.0f; }

// ---------------- prep kernels ----------------

// e_bf[m=t*64+b][k] = bf16(emb[x[b][t]][k]);  thread = (m, koct)
__global__ void prep_e(const int* __restrict__ x, const float* __restrict__ emb,
                       unsigned short* __restrict__ ebf) {
  int idx = blockIdx.x * 256 + threadIdx.x;   // [0, 8192*32)
  int koct = idx & 31;
  int m = idx >> 5;
  int t = m >> 6, b = m & 63;
  int tok = x[b * 128 + t];
  const float* src = emb + (size_t)tok * 256 + (size_t)koct * 8;
  short8 v;
#pragma unroll
  for (int j = 0; j < 8; ++j) v[j] = (short)f2bf(src[j]);
  *(short8*)(ebf + (size_t)m * 256 + koct * 8) = v;
}

// Wt[n][k] = bf16(W[k][n]);  W is [K][4096]; thread = (n fast, koct)
__global__ void prep_wt(const float* __restrict__ W, unsigned short* __restrict__ Wt, int K) {
  int idx = blockIdx.x * 256 + threadIdx.x;   // [0, 4096*(K/8))
  int n = idx & 4095;
  int koct = idx >> 12;
  short8 v;
#pragma unroll
  for (int j = 0; j < 8; ++j) v[j] = (short)f2bf(W[(size_t)(koct * 8 + j) * 4096 + n]);
  *(short8*)(Wt + (size_t)n * K + koct * 8) = v;
}

// d[i] = bf16(s[i]), 65536 elements
__global__ void prep_cvt(const float* __restrict__ s, unsigned short* __restrict__ d) {
  int i = blockIdx.x * 256 + threadIdx.x;
  d[i] = f2bf(s[i]);
}

// ---------------- GEMM: xz = A @ Bt^T + bias, output in block-sliced bf16 layout ----------------
// A: [M=8192][K] bf16 row-major (rows m = t*64+b). Bt: [4096][K] bf16 (n-major, k contiguous).
// xz elem index: ((t*256 + bid)*64 + b)*16 + jj*4 + gate,  n = gate*1024 + bid*4 + jj.
__global__ __launch_bounds__(256) void gemm_xz(
    const unsigned short* __restrict__ A,
    const unsigned short* __restrict__ Bt,
    const float* __restrict__ bias,
    unsigned short* __restrict__ xz, int K) {
  __shared__ __align__(16) unsigned short Alds[128 * 32];
  __shared__ __align__(16) unsigned short Blds[128 * 32];
  const int tid = threadIdx.x;
  const int w = tid >> 6, l = tid & 63;
  const int m0 = blockIdx.x * 128;
  const int n0 = blockIdx.y * 128;
  const int mw = (w >> 1) * 64, nw = (w & 1) * 64;
  floatx4 acc[4][4];
#pragma unroll
  for (int i = 0; i < 4; ++i)
#pragma unroll
    for (int jq = 0; jq < 4; ++jq) acc[i][jq] = (floatx4){0.f, 0.f, 0.f, 0.f};

  const int ktiles = K >> 5;
  for (int kt = 0; kt < ktiles; ++kt) {
#pragma unroll
    for (int i = 0; i < 2; ++i) {
      int off = (w * 2 + i) * 1024 + l * 16;    // byte offset in 8KB tile
      int row = off >> 6, colb = off & 63;
      const char* gA = (const char*)A + ((size_t)(m0 + row) * K) * 2 + (size_t)kt * 64 + colb;
      __builtin_amdgcn_global_load_lds((const GLOBAL_AS void*)gA,
                                       (LDS_AS void*)((char*)Alds + off), 16, 0, 0);
      const char* gB = (const char*)Bt + ((size_t)(n0 + row) * K) * 2 + (size_t)kt * 64 + colb;
      __builtin_amdgcn_global_load_lds((const GLOBAL_AS void*)gB,
                                       (LDS_AS void*)((char*)Blds + off), 16, 0, 0);
    }
    __syncthreads();
    short8 af[4], bfr[4];
#pragma unroll
    for (int s = 0; s < 4; ++s) {
      af[s]  = *(const short8*)&Alds[(mw + s * 16 + (l & 15)) * 32 + (l >> 4) * 8];
      bfr[s] = *(const short8*)&Blds[(nw + s * 16 + (l & 15)) * 32 + (l >> 4) * 8];
    }
#pragma unroll
    for (int si = 0; si < 4; ++si)
#pragma unroll
      for (int sj = 0; sj < 4; ++sj)
        acc[si][sj] = __builtin_amdgcn_mfma_f32_16x16x32_bf16(af[si], bfr[sj], acc[si][sj], 0, 0, 0);
    __syncthreads();
  }
  // epilogue: D row=(l>>4)*4+r (m), col=l&15 (n)
#pragma unroll
  for (int sj = 0; sj < 4; ++sj) {
    const int n = n0 + nw + sj * 16 + (l & 15);
    const float bv = bias[n];
    const int gate = n >> 10;
    const int bidx = (n & 1023) >> 2;
    const int jjj = n & 3;
#pragma unroll
    for (int si = 0; si < 4; ++si) {
#pragma unroll
      for (int r = 0; r < 4; ++r) {
        const int m = m0 + mw + si * 16 + ((l >> 4) << 2) + r;
        const int t = m >> 6, b = m & 63;
        xz[(size_t)t * 262144 + (size_t)bidx * 1024 + b * 16 + jjj * 4 + gate] =
            f2bf(acc[si][sj][r] + bv);
      }
    }
  }
}

// ---------------- cooperative LSTM recurrence ----------------
// Block bid owns h-cols j = 4*bid .. 4*bid+3 (for each of 4 gates -> 16 U columns).
// z computed transposed: D[m=packed col (jj*4+gate)][n=batch] so each lane's 4 acc regs
// are (i,f,g,o) for one (b, j). U packed in LDS in exact A-fragment order.
__global__ __launch_bounds__(256) void lstm_recur(
    const float* __restrict__ U,          // [1024][4096] fp32
    const unsigned short* __restrict__ xz,
    unsigned short* __restrict__ hhist,   // [129][64][1024] bf16, slab 0 prefilled
    const float* __restrict__ c0,         // [64][1024]
    float* __restrict__ outy,             // [64][128][1024] fp32 or nullptr
    float* __restrict__ hT,
    float* __restrict__ cT) {
  __shared__ __align__(16) unsigned short Ulds[32 * 64 * 8]; // 32KB, [ks][lane][8]
  const int bid = blockIdx.x;
  const int tid = threadIdx.x;
  const int w = tid >> 6, l = tid & 63;

  // pack U columns into LDS in A-fragment order (one-time)
  for (int run = tid; run < 2048; run += 256) {
    const int ll = run & 63;
    const int ks = run >> 6;
    const int m = ll & 15;
    const int jjp = m >> 2, gate = m & 3;
    const int n = gate * 1024 + bid * 4 + jjp;
    const int kb = ks * 32 + (ll >> 4) * 8;
    short8 v;
#pragma unroll
    for (int jq = 0; jq < 8; ++jq) v[jq] = (short)f2bf(U[(size_t)(kb + jq) * 4096 + n]);
    *(short8*)&Ulds[(size_t)run * 8] = v;
  }
  __syncthreads();

  const int b = w * 16 + (l & 15);
  const int jj = l >> 4;
  const int j = bid * 4 + jj;
  float c = c0[b * 1024 + j];
  const int kq = (l >> 4) * 8;

  cg::grid_group grid = cg::this_grid();

  for (int t = 0; t < 128; ++t) {
    const unsigned short* hrow = hhist + (size_t)t * 65536 + (size_t)b * 1024;
    floatx4 a0 = {0.f, 0.f, 0.f, 0.f}, a1 = a0, a2 = a0, a3 = a0;
#pragma unroll 2
    for (int ks = 0; ks < 32; ks += 4) {
      short8 u0 = *(const short8*)&Ulds[((ks + 0) * 64 + l) * 8];
      short8 u1 = *(const short8*)&Ulds[((ks + 1) * 64 + l) * 8];
      short8 u2 = *(const short8*)&Ulds[((ks + 2) * 64 + l) * 8];
      short8 u3 = *(const short8*)&Ulds[((ks + 3) * 64 + l) * 8];
      short8 hv0 = *(const short8*)&hrow[(ks + 0) * 32 + kq];
      short8 hv1 = *(const short8*)&hrow[(ks + 1) * 32 + kq];
      short8 hv2 = *(const short8*)&hrow[(ks + 2) * 32 + kq];
      short8 hv3 = *(const short8*)&hrow[(ks + 3) * 32 + kq];
      a0 = __builtin_amdgcn_mfma_f32_16x16x32_bf16(u0, hv0, a0, 0, 0, 0);
      a1 = __builtin_amdgcn_mfma_f32_16x16x32_bf16(u1, hv1, a1, 0, 0, 0);
      a2 = __builtin_amdgcn_mfma_f32_16x16x32_bf16(u2, hv2, a2, 0, 0, 0);
      a3 = __builtin_amdgcn_mfma_f32_16x16x32_bf16(u3, hv3, a3, 0, 0, 0);
    }
    floatx4 acc = (a0 + a1) + (a2 + a3);
    const unsigned short* xzp = xz + (size_t)t * 262144 + (size_t)bid * 1024 + b * 16 + jj * 4;
    ushort4 xv = *(const ushort4*)xzp;
    float zi = acc[0] + bf2f(xv.x);
    float zf = acc[1] + bf2f(xv.y);
    float zg = acc[2] + bf2f(xv.z);
    float zo = acc[3] + bf2f(xv.w);
    float ig = sigm(zi), fg = sigm(zf), gg = tanh_f(zg), og = sigm(zo);
    c = fg * c + ig * gg;
    float h = og * tanh_f(c);
    hhist[(size_t)(t + 1) * 65536 + (size_t)b * 1024 + j] = f2bf(h);
    if (outy) outy[(size_t)b * 131072 + (size_t)t * 1024 + j] = h;
    if (t == 127) { hT[b * 1024 + j] = h; cT[b * 1024 + j] = c; }
    grid.sync();
  }
}

// ---------------- launch ----------------
extern "C" void kernel_launch(void* const* d_in, const int* in_sizes, int n_in,
                              void* d_out, int out_size, void* d_ws, size_t ws_size,
                              hipStream_t stream) {
  const int*   x    = (const int*)d_in[0];
  const float* h0_1 = (const float*)d_in[1];
  const float* c0_1 = (const float*)d_in[2];
  const float* h0_2 = (const float*)d_in[3];
  const float* c0_2 = (const float*)d_in[4];
  const float* emb  = (const float*)d_in[5];
  const float* W1   = (const float*)d_in[6];
  const float* U1   = (const float*)d_in[7];
  const float* b1   = (const float*)d_in[8];
  const float* W2   = (const float*)d_in[9];
  const float* U2   = (const float*)d_in[10];
  const float* b2   = (const float*)d_in[11];
  float* outf = (float*)d_out;

  unsigned short* ws  = (unsigned short*)d_ws;
  unsigned short* ebf = ws;                    // 2,097,152
  unsigned short* W1t = ws + 2097152;          // 1,048,576
  unsigned short* W2t = ws + 3145728;          // 4,194,304
  unsigned short* xz  = ws + 7340032;          // 33,554,432
  unsigned short* h1h = ws + 40894464;         // 8,454,144
  unsigned short* h2h = ws + 49348608;         // 8,454,144  (end 57,802,752 ush = 115.6 MB)

  float* hT1 = outf + 8388608;
  float* cT1 = outf + 8454144;
  float* hT2 = outf + 8519680;
  float* cT2 = outf + 8585216;

  prep_e<<<1024, 256, 0, stream>>>(x, emb, ebf);
  prep_wt<<<512, 256, 0, stream>>>(W1, W1t, 256);
  prep_wt<<<2048, 256, 0, stream>>>(W2, W2t, 1024);
  prep_cvt<<<256, 256, 0, stream>>>(h0_1, h1h);
  prep_cvt<<<256, 256, 0, stream>>>(h0_2, h2h);

  gemm_xz<<<dim3(64, 32), 256, 0, stream>>>(ebf, W1t, b1, xz, 256);

  {
    const float* Uc = U1; const unsigned short* xzc = xz; unsigned short* hh = h1h;
    const float* c0c = c0_1; float* oy = nullptr; float* ht = hT1; float* ct = cT1;
    void* args[] = {&Uc, &xzc, &hh, &c0c, &oy, &ht, &ct};
    hipLaunchCooperativeKernel((void*)lstm_recur, dim3(256), dim3(256), args, 0, stream);
  }

  gemm_xz<<<dim3(64, 32), 256, 0, stream>>>(h1h + 65536, W2t, b2, xz, 1024);

  {
    const float* Uc = U2; const unsigned short* xzc = xz; unsigned short* hh = h2h;
    const float* c0c = c0_2; float* oy = outf; float* ht = hT2; float* ct = cT2;
    void* args[] = {&Uc, &xzc, &hh, &c0c, &oy, &ht, &ct};
    hipLaunchCooperativeKernel((void*)lstm_recur, dim3(256), dim3(256), args, 0, stream);
  }
}

// Round 2
// 3973.036 us; speedup vs baseline: 2.2833x; 2.2833x over previous
//
#include <hip/hip_runtime.h>

typedef __attribute__((ext_vector_type(8))) short short8;
typedef __attribute__((ext_vector_type(4))) float floatx4;

#define GLOBAL_AS __attribute__((address_space(1)))
#define LDS_AS    __attribute__((address_space(3)))

__device__ __forceinline__ float bf2f(unsigned short u) {
  union { float f; unsigned int i; } v; v.i = ((unsigned int)u) << 16; return v.f;
}
__device__ __forceinline__ unsigned short f2bf(float f) {
  union { float f; unsigned int i; } v; v.f = f;
  unsigned int r = (v.i + 0x7fffu + ((v.i >> 16) & 1u)) >> 16;
  return (unsigned short)r;
}
__device__ __forceinline__ float sigm(float x) { return 1.0f / (1.0f + __expf(-x)); }
__device__ __forceinline__ float tanh_f(float x) { return 2.0f * sigm(2.0f * x) - 1.0f; }

// ---------------- custom grid barrier (sense-reversing, agent scope) ----------------
// cnt at bar[0], gen at bar[32] (separate 128B lines). All NBLK blocks call this
// the same number of times. Caller must ensure bar[] starts zeroed (cnt returns to
// 0 after every completed barrier; gen is monotonic and read fresh each time).
__device__ __forceinline__ void gridbar(unsigned int* bar, unsigned int nblk) {
  __syncthreads();                      // drains this block's stores (vmcnt 0)
  if (threadIdx.x == 0) {
    __builtin_amdgcn_fence(__ATOMIC_RELEASE, "agent");   // wb L2 -> h visible
    unsigned int* cnt = bar;
    unsigned int* gen = bar + 32;
    unsigned int g = __hip_atomic_load(gen, __ATOMIC_RELAXED, __HIP_MEMORY_SCOPE_AGENT);
    unsigned int a = __hip_atomic_fetch_add(cnt, 1u, __ATOMIC_RELAXED, __HIP_MEMORY_SCOPE_AGENT);
    if (a == nblk - 1u) {
      __hip_atomic_store(cnt, 0u, __ATOMIC_RELAXED, __HIP_MEMORY_SCOPE_AGENT);
      __hip_atomic_store(gen, g + 1u, __ATOMIC_RELEASE, __HIP_MEMORY_SCOPE_AGENT);
    } else {
      while (__hip_atomic_load(gen, __ATOMIC_RELAXED, __HIP_MEMORY_SCOPE_AGENT) == g) {
        __builtin_amdgcn_s_sleep(2);
      }
    }
    __builtin_amdgcn_fence(__ATOMIC_ACQUIRE, "agent");   // inv stale L1/L2
  }
  __syncthreads();
}

__global__ void zero_bar(unsigned int* bar) {
  if (threadIdx.x < 64) bar[threadIdx.x] = 0u;
}

// ---------------- prep kernels ----------------

__global__ void prep_e(const int* __restrict__ x, const float* __restrict__ emb,
                       unsigned short* __restrict__ ebf) {
  int idx = blockIdx.x * 256 + threadIdx.x;   // [0, 8192*32)
  int koct = idx & 31;
  int m = idx >> 5;
  int t = m >> 6, b = m & 63;
  int tok = x[b * 128 + t];
  const float* src = emb + (size_t)tok * 256 + (size_t)koct * 8;
  short8 v;
#pragma unroll
  for (int j = 0; j < 8; ++j) v[j] = (short)f2bf(src[j]);
  *(short8*)(ebf + (size_t)m * 256 + koct * 8) = v;
}

__global__ void prep_wt(const float* __restrict__ W, unsigned short* __restrict__ Wt, int K) {
  int idx = blockIdx.x * 256 + threadIdx.x;   // [0, 4096*(K/8))
  int n = idx & 4095;
  int koct = idx >> 12;
  short8 v;
#pragma unroll
  for (int j = 0; j < 8; ++j) v[j] = (short)f2bf(W[(size_t)(koct * 8 + j) * 4096 + n]);
  *(short8*)(Wt + (size_t)n * K + koct * 8) = v;
}

__global__ void prep_cvt(const float* __restrict__ s, unsigned short* __restrict__ d) {
  int i = blockIdx.x * 256 + threadIdx.x;
  d[i] = f2bf(s[i]);
}

// ---------------- GEMM: xz = A @ Bt^T + bias, block-sliced bf16 output ----------------
__global__ __launch_bounds__(256) void gemm_xz(
    const unsigned short* __restrict__ A,
    const unsigned short* __restrict__ Bt,
    const float* __restrict__ bias,
    unsigned short* __restrict__ xz, int K) {
  __shared__ __align__(16) unsigned short Alds[128 * 32];
  __shared__ __align__(16) unsigned short Blds[128 * 32];
  const int tid = threadIdx.x;
  const int w = tid >> 6, l = tid & 63;
  const int m0 = blockIdx.x * 128;
  const int n0 = blockIdx.y * 128;
  const int mw = (w >> 1) * 64, nw = (w & 1) * 64;
  floatx4 acc[4][4];
#pragma unroll
  for (int i = 0; i < 4; ++i)
#pragma unroll
    for (int jq = 0; jq < 4; ++jq) acc[i][jq] = (floatx4){0.f, 0.f, 0.f, 0.f};

  const int ktiles = K >> 5;
  for (int kt = 0; kt < ktiles; ++kt) {
#pragma unroll
    for (int i = 0; i < 2; ++i) {
      int off = (w * 2 + i) * 1024 + l * 16;
      int row = off >> 6, colb = off & 63;
      const char* gA = (const char*)A + ((size_t)(m0 + row) * K) * 2 + (size_t)kt * 64 + colb;
      __builtin_amdgcn_global_load_lds((const GLOBAL_AS void*)gA,
                                       (LDS_AS void*)((char*)Alds + off), 16, 0, 0);
      const char* gB = (const char*)Bt + ((size_t)(n0 + row) * K) * 2 + (size_t)kt * 64 + colb;
      __builtin_amdgcn_global_load_lds((const GLOBAL_AS void*)gB,
                                       (LDS_AS void*)((char*)Blds + off), 16, 0, 0);
    }
    __syncthreads();
    short8 af[4], bfr[4];
#pragma unroll
    for (int s = 0; s < 4; ++s) {
      af[s]  = *(const short8*)&Alds[(mw + s * 16 + (l & 15)) * 32 + (l >> 4) * 8];
      bfr[s] = *(const short8*)&Blds[(nw + s * 16 + (l & 15)) * 32 + (l >> 4) * 8];
    }
#pragma unroll
    for (int si = 0; si < 4; ++si)
#pragma unroll
      for (int sj = 0; sj < 4; ++sj)
        acc[si][sj] = __builtin_amdgcn_mfma_f32_16x16x32_bf16(af[si], bfr[sj], acc[si][sj], 0, 0, 0);
    __syncthreads();
  }
#pragma unroll
  for (int sj = 0; sj < 4; ++sj) {
    const int n = n0 + nw + sj * 16 + (l & 15);
    const float bv = bias[n];
    const int gate = n >> 10;
    const int bidx = (n & 1023) >> 2;
    const int jjj = n & 3;
#pragma unroll
    for (int si = 0; si < 4; ++si) {
#pragma unroll
      for (int r = 0; r < 4; ++r) {
        const int m = m0 + mw + si * 16 + ((l >> 4) << 2) + r;
        const int t = m >> 6, b = m & 63;
        xz[(size_t)t * 262144 + (size_t)bidx * 1024 + b * 16 + jjj * 4 + gate] =
            f2bf(acc[si][sj][r] + bv);
      }
    }
  }
}

// ---------------- cooperative LSTM recurrence (custom barrier) ----------------
__global__ __launch_bounds__(256) void lstm_recur(
    const float* __restrict__ U,          // [1024][4096] fp32
    const unsigned short* __restrict__ xz,
    unsigned short* __restrict__ hhist,   // [129][64][1024] bf16, slab 0 prefilled
    const float* __restrict__ c0,         // [64][1024]
    float* __restrict__ outy,             // [64][128][1024] fp32 or nullptr
    float* __restrict__ hT,
    float* __restrict__ cT,
    unsigned int* __restrict__ bar) {
  __shared__ __align__(16) unsigned short Ulds[32 * 64 * 8]; // 32KB, [ks][lane][8]
  const int bid = blockIdx.x;
  const int tid = threadIdx.x;
  const int w = tid >> 6, l = tid & 63;

  for (int run = tid; run < 2048; run += 256) {
    const int ll = run & 63;
    const int ks = run >> 6;
    const int m = ll & 15;
    const int jjp = m >> 2, gate = m & 3;
    const int n = gate * 1024 + bid * 4 + jjp;
    const int kb = ks * 32 + (ll >> 4) * 8;
    short8 v;
#pragma unroll
    for (int jq = 0; jq < 8; ++jq) v[jq] = (short)f2bf(U[(size_t)(kb + jq) * 4096 + n]);
    *(short8*)&Ulds[(size_t)run * 8] = v;
  }
  __syncthreads();

  const int b = w * 16 + (l & 15);
  const int jj = l >> 4;
  const int j = bid * 4 + jj;
  float c = c0[b * 1024 + j];
  const int kq = (l >> 4) * 8;

  for (int t = 0; t < 128; ++t) {
    const unsigned short* hrow = hhist + (size_t)t * 65536 + (size_t)b * 1024;
    floatx4 a0 = {0.f, 0.f, 0.f, 0.f}, a1 = a0, a2 = a0, a3 = a0;
#pragma unroll 2
    for (int ks = 0; ks < 32; ks += 4) {
      short8 u0 = *(const short8*)&Ulds[((ks + 0) * 64 + l) * 8];
      short8 u1 = *(const short8*)&Ulds[((ks + 1) * 64 + l) * 8];
      short8 u2 = *(const short8*)&Ulds[((ks + 2) * 64 + l) * 8];
      short8 u3 = *(const short8*)&Ulds[((ks + 3) * 64 + l) * 8];
      short8 hv0 = *(const short8*)&hrow[(ks + 0) * 32 + kq];
      short8 hv1 = *(const short8*)&hrow[(ks + 1) * 32 + kq];
      short8 hv2 = *(const short8*)&hrow[(ks + 2) * 32 + kq];
      short8 hv3 = *(const short8*)&hrow[(ks + 3) * 32 + kq];
      a0 = __builtin_amdgcn_mfma_f32_16x16x32_bf16(u0, hv0, a0, 0, 0, 0);
      a1 = __builtin_amdgcn_mfma_f32_16x16x32_bf16(u1, hv1, a1, 0, 0, 0);
      a2 = __builtin_amdgcn_mfma_f32_16x16x32_bf16(u2, hv2, a2, 0, 0, 0);
      a3 = __builtin_amdgcn_mfma_f32_16x16x32_bf16(u3, hv3, a3, 0, 0, 0);
    }
    floatx4 acc = (a0 + a1) + (a2 + a3);
    const unsigned short* xzp = xz + (size_t)t * 262144 + (size_t)bid * 1024 + b * 16 + jj * 4;
    ushort4 xv = *(const ushort4*)xzp;
    float zi = acc[0] + bf2f(xv.x);
    float zf = acc[1] + bf2f(xv.y);
    float zg = acc[2] + bf2f(xv.z);
    float zo = acc[3] + bf2f(xv.w);
    float ig = sigm(zi), fg = sigm(zf), gg = tanh_f(zg), og = sigm(zo);
    c = fg * c + ig * gg;
    float h = og * tanh_f(c);
    hhist[(size_t)(t + 1) * 65536 + (size_t)b * 1024 + j] = f2bf(h);
    if (outy) outy[(size_t)b * 131072 + (size_t)t * 1024 + j] = h;
    if (t == 127) { hT[b * 1024 + j] = h; cT[b * 1024 + j] = c; }
    if (t != 127) gridbar(bar, 256u);   // last step: kernel boundary provides visibility
  }
}

// ---------------- launch ----------------
extern "C" void kernel_launch(void* const* d_in, const int* in_sizes, int n_in,
                              void* d_out, int out_size, void* d_ws, size_t ws_size,
                              hipStream_t stream) {
  const int*   x    = (const int*)d_in[0];
  const float* c0_1 = (const float*)d_in[2];
  const float* c0_2 = (const float*)d_in[4];
  const float* emb  = (const float*)d_in[5];
  const float* W1   = (const float*)d_in[6];
  const float* U1   = (const float*)d_in[7];
  const float* b1   = (const float*)d_in[8];
  const float* W2   = (const float*)d_in[9];
  const float* U2   = (const float*)d_in[10];
  const float* b2   = (const float*)d_in[11];
  float* outf = (float*)d_out;

  unsigned short* ws  = (unsigned short*)d_ws;
  unsigned short* ebf = ws;                    // 2,097,152
  unsigned short* W1t = ws + 2097152;          // 1,048,576
  unsigned short* W2t = ws + 3145728;          // 4,194,304
  unsigned short* xz  = ws + 7340032;          // 33,554,432
  unsigned short* h1h = ws + 40894464;         // 8,454,144
  unsigned short* h2h = ws + 49348608;         // 8,454,144
  unsigned int*   bar = (unsigned int*)(ws + 57802752);  // 256B barrier area

  float* hT1 = outf + 8388608;
  float* cT1 = outf + 8454144;
  float* hT2 = outf + 8519680;
  float* cT2 = outf + 8585216;

  zero_bar<<<1, 64, 0, stream>>>(bar);
  prep_e<<<1024, 256, 0, stream>>>(x, emb, ebf);
  prep_wt<<<512, 256, 0, stream>>>(W1, W1t, 256);
  prep_wt<<<2048, 256, 0, stream>>>(W2, W2t, 1024);
  prep_cvt<<<256, 256, 0, stream>>>(d_in[1] /*h0_1*/ ? (const float*)d_in[1] : nullptr, h1h);
  prep_cvt<<<256, 256, 0, stream>>>((const float*)d_in[3] /*h0_2*/, h2h);

  gemm_xz<<<dim3(64, 32), 256, 0, stream>>>(ebf, W1t, b1, xz, 256);

  {
    const float* Uc = U1; const unsigned short* xzc = xz; unsigned short* hh = h1h;
    const float* c0c = c0_1; float* oy = nullptr; float* ht = hT1; float* ct = cT1;
    unsigned int* brc = bar;
    void* args[] = {&Uc, &xzc, &hh, &c0c, &oy, &ht, &ct, &brc};
    hipLaunchCooperativeKernel((void*)lstm_recur, dim3(256), dim3(256), args, 0, stream);
  }

  gemm_xz<<<dim3(64, 32), 256, 0, stream>>>(h1h + 65536, W2t, b2, xz, 1024);

  {
    const float* Uc = U2; const unsigned short* xzc = xz; unsigned short* hh = h2h;
    const float* c0c = c0_2; float* oy = outf; float* ht = hT2; float* ct = cT2;
    unsigned int* brc = bar;
    void* args[] = {&Uc, &xzc, &hh, &c0c, &oy, &ht, &ct, &brc};
    hipLaunchCooperativeKernel((void*)lstm_recur, dim3(256), dim3(256), args, 0, stream);
  }
}

// Round 3
// 3112.850 us; speedup vs baseline: 2.9143x; 1.2763x over previous
//
#include <hip/hip_runtime.h>

typedef __attribute__((ext_vector_type(8))) short short8;
typedef __attribute__((ext_vector_type(4))) float floatx4;

#define GLOBAL_AS __attribute__((address_space(1)))
#define LDS_AS    __attribute__((address_space(3)))

__device__ __forceinline__ float bf2f(unsigned short u) {
  union { float f; unsigned int i; } v; v.i = ((unsigned int)u) << 16; return v.f;
}
__device__ __forceinline__ unsigned short f2bf(float f) {
  union { float f; unsigned int i; } v; v.f = f;
  unsigned int r = (v.i + 0x7fffu + ((v.i >> 16) & 1u)) >> 16;
  return (unsigned short)r;
}
__device__ __forceinline__ float sigm(float x) { return 1.0f / (1.0f + __expf(-x)); }
__device__ __forceinline__ float tanh_f(float x) { return 2.0f * sigm(2.0f * x) - 1.0f; }

// ---------------- atomic-free grid barrier ----------------
// bar[0..255]: per-block monotonic phase flags. bar[512]: gen word (own line).
// Block 0 is the checker: its 256 threads poll one flag each; when all >= phase
// it publishes gen=phase. No atomic RMW anywhere -> no same-line serialization.
__device__ __forceinline__ void gridbar(unsigned int* bar, unsigned int phase) {
  // each wave drains its own outstanding stores (incl. h writes) before arrival
  asm volatile("s_waitcnt vmcnt(0)" ::: "memory");
  __syncthreads();
  unsigned int* flags = bar;
  unsigned int* gen = bar + 512;
  if (threadIdx.x == 0) {
    __builtin_amdgcn_fence(__ATOMIC_RELEASE, "agent");   // wb L2: h visible at LLC
    __hip_atomic_store(&flags[blockIdx.x], phase, __ATOMIC_RELAXED, __HIP_MEMORY_SCOPE_AGENT);
  }
  if (blockIdx.x == 0) {
    unsigned int v;
    do {
      v = __hip_atomic_load(&flags[threadIdx.x], __ATOMIC_RELAXED, __HIP_MEMORY_SCOPE_AGENT);
      if (v < phase) __builtin_amdgcn_s_sleep(1);
    } while (v < phase);
    __syncthreads();
    if (threadIdx.x == 0)
      __hip_atomic_store(gen, phase, __ATOMIC_RELAXED, __HIP_MEMORY_SCOPE_AGENT);
  }
  if (threadIdx.x == 0) {
    while (__hip_atomic_load(gen, __ATOMIC_RELAXED, __HIP_MEMORY_SCOPE_AGENT) < phase)
      __builtin_amdgcn_s_sleep(1);
    __builtin_amdgcn_fence(__ATOMIC_ACQUIRE, "agent");   // inv stale L1/L2
  }
  __syncthreads();
}

__global__ void zero_bar(unsigned int* bar) {
  int i = blockIdx.x * 256 + threadIdx.x;
  if (i < 1024) bar[i] = 0u;
}

// ---------------- prep kernels ----------------

__global__ void prep_e(const int* __restrict__ x, const float* __restrict__ emb,
                       unsigned short* __restrict__ ebf) {
  int idx = blockIdx.x * 256 + threadIdx.x;   // [0, 8192*32)
  int koct = idx & 31;
  int m = idx >> 5;
  int t = m >> 6, b = m & 63;
  int tok = x[b * 128 + t];
  const float* src = emb + (size_t)tok * 256 + (size_t)koct * 8;
  short8 v;
#pragma unroll
  for (int j = 0; j < 8; ++j) v[j] = (short)f2bf(src[j]);
  *(short8*)(ebf + (size_t)m * 256 + koct * 8) = v;
}

__global__ void prep_wt(const float* __restrict__ W, unsigned short* __restrict__ Wt, int K) {
  int idx = blockIdx.x * 256 + threadIdx.x;   // [0, 4096*(K/8))
  int n = idx & 4095;
  int koct = idx >> 12;
  short8 v;
#pragma unroll
  for (int j = 0; j < 8; ++j) v[j] = (short)f2bf(W[(size_t)(koct * 8 + j) * 4096 + n]);
  *(short8*)(Wt + (size_t)n * K + koct * 8) = v;
}

__global__ void prep_cvt(const float* __restrict__ s, unsigned short* __restrict__ d) {
  int i = blockIdx.x * 256 + threadIdx.x;
  d[i] = f2bf(s[i]);
}

// ---------------- GEMM: xz = A @ Bt^T + bias, block-sliced bf16 output ----------------
__global__ __launch_bounds__(256) void gemm_xz(
    const unsigned short* __restrict__ A,
    const unsigned short* __restrict__ Bt,
    const float* __restrict__ bias,
    unsigned short* __restrict__ xz, int K) {
  __shared__ __align__(16) unsigned short Alds[128 * 32];
  __shared__ __align__(16) unsigned short Blds[128 * 32];
  const int tid = threadIdx.x;
  const int w = tid >> 6, l = tid & 63;
  const int m0 = blockIdx.x * 128;
  const int n0 = blockIdx.y * 128;
  const int mw = (w >> 1) * 64, nw = (w & 1) * 64;
  floatx4 acc[4][4];
#pragma unroll
  for (int i = 0; i < 4; ++i)
#pragma unroll
    for (int jq = 0; jq < 4; ++jq) acc[i][jq] = (floatx4){0.f, 0.f, 0.f, 0.f};

  const int ktiles = K >> 5;
  for (int kt = 0; kt < ktiles; ++kt) {
#pragma unroll
    for (int i = 0; i < 2; ++i) {
      int off = (w * 2 + i) * 1024 + l * 16;
      int row = off >> 6, colb = off & 63;
      const char* gA = (const char*)A + ((size_t)(m0 + row) * K) * 2 + (size_t)kt * 64 + colb;
      __builtin_amdgcn_global_load_lds((const GLOBAL_AS void*)gA,
                                       (LDS_AS void*)((char*)Alds + off), 16, 0, 0);
      const char* gB = (const char*)Bt + ((size_t)(n0 + row) * K) * 2 + (size_t)kt * 64 + colb;
      __builtin_amdgcn_global_load_lds((const GLOBAL_AS void*)gB,
                                       (LDS_AS void*)((char*)Blds + off), 16, 0, 0);
    }
    __syncthreads();
    short8 af[4], bfr[4];
#pragma unroll
    for (int s = 0; s < 4; ++s) {
      af[s]  = *(const short8*)&Alds[(mw + s * 16 + (l & 15)) * 32 + (l >> 4) * 8];
      bfr[s] = *(const short8*)&Blds[(nw + s * 16 + (l & 15)) * 32 + (l >> 4) * 8];
    }
#pragma unroll
    for (int si = 0; si < 4; ++si)
#pragma unroll
      for (int sj = 0; sj < 4; ++sj)
        acc[si][sj] = __builtin_amdgcn_mfma_f32_16x16x32_bf16(af[si], bfr[sj], acc[si][sj], 0, 0, 0);
    __syncthreads();
  }
#pragma unroll
  for (int sj = 0; sj < 4; ++sj) {
    const int n = n0 + nw + sj * 16 + (l & 15);
    const float bv = bias[n];
    const int gate = n >> 10;
    const int bidx = (n & 1023) >> 2;
    const int jjj = n & 3;
#pragma unroll
    for (int si = 0; si < 4; ++si) {
#pragma unroll
      for (int r = 0; r < 4; ++r) {
        const int m = m0 + mw + si * 16 + ((l >> 4) << 2) + r;
        const int t = m >> 6, b = m & 63;
        xz[(size_t)t * 262144 + (size_t)bidx * 1024 + b * 16 + jjj * 4 + gate] =
            f2bf(acc[si][sj][r] + bv);
      }
    }
  }
}

// ---------------- cooperative LSTM recurrence (flag barrier) ----------------
__global__ __launch_bounds__(256) void lstm_recur(
    const float* __restrict__ U,          // [1024][4096] fp32
    const unsigned short* __restrict__ xz,
    unsigned short* __restrict__ hhist,   // [129][64][1024] bf16, slab 0 prefilled
    const float* __restrict__ c0,         // [64][1024]
    float* __restrict__ outy,             // [64][128][1024] fp32 or nullptr
    float* __restrict__ hT,
    float* __restrict__ cT,
    unsigned int* __restrict__ bar,
    unsigned int phase_base) {
  __shared__ __align__(16) unsigned short Ulds[32 * 64 * 8]; // 32KB, [ks][lane][8]
  const int bid = blockIdx.x;
  const int tid = threadIdx.x;
  const int w = tid >> 6, l = tid & 63;

  for (int run = tid; run < 2048; run += 256) {
    const int ll = run & 63;
    const int ks = run >> 6;
    const int m = ll & 15;
    const int jjp = m >> 2, gate = m & 3;
    const int n = gate * 1024 + bid * 4 + jjp;
    const int kb = ks * 32 + (ll >> 4) * 8;
    short8 v;
#pragma unroll
    for (int jq = 0; jq < 8; ++jq) v[jq] = (short)f2bf(U[(size_t)(kb + jq) * 4096 + n]);
    *(short8*)&Ulds[(size_t)run * 8] = v;
  }
  __syncthreads();

  const int b = w * 16 + (l & 15);
  const int jj = l >> 4;
  const int j = bid * 4 + jj;
  float c = c0[b * 1024 + j];
  const int kq = (l >> 4) * 8;

  for (int t = 0; t < 128; ++t) {
    const unsigned short* hrow = hhist + (size_t)t * 65536 + (size_t)b * 1024;
    floatx4 a0 = {0.f, 0.f, 0.f, 0.f}, a1 = a0, a2 = a0, a3 = a0;
#pragma unroll 2
    for (int ks = 0; ks < 32; ks += 4) {
      short8 u0 = *(const short8*)&Ulds[((ks + 0) * 64 + l) * 8];
      short8 u1 = *(const short8*)&Ulds[((ks + 1) * 64 + l) * 8];
      short8 u2 = *(const short8*)&Ulds[((ks + 2) * 64 + l) * 8];
      short8 u3 = *(const short8*)&Ulds[((ks + 3) * 64 + l) * 8];
      short8 hv0 = *(const short8*)&hrow[(ks + 0) * 32 + kq];
      short8 hv1 = *(const short8*)&hrow[(ks + 1) * 32 + kq];
      short8 hv2 = *(const short8*)&hrow[(ks + 2) * 32 + kq];
      short8 hv3 = *(const short8*)&hrow[(ks + 3) * 32 + kq];
      a0 = __builtin_amdgcn_mfma_f32_16x16x32_bf16(u0, hv0, a0, 0, 0, 0);
      a1 = __builtin_amdgcn_mfma_f32_16x16x32_bf16(u1, hv1, a1, 0, 0, 0);
      a2 = __builtin_amdgcn_mfma_f32_16x16x32_bf16(u2, hv2, a2, 0, 0, 0);
      a3 = __builtin_amdgcn_mfma_f32_16x16x32_bf16(u3, hv3, a3, 0, 0, 0);
    }
    floatx4 acc = (a0 + a1) + (a2 + a3);
    const unsigned short* xzp = xz + (size_t)t * 262144 + (size_t)bid * 1024 + b * 16 + jj * 4;
    ushort4 xv = *(const ushort4*)xzp;
    float zi = acc[0] + bf2f(xv.x);
    float zf = acc[1] + bf2f(xv.y);
    float zg = acc[2] + bf2f(xv.z);
    float zo = acc[3] + bf2f(xv.w);
    float ig = sigm(zi), fg = sigm(zf), gg = tanh_f(zg), og = sigm(zo);
    c = fg * c + ig * gg;
    float h = og * tanh_f(c);
    hhist[(size_t)(t + 1) * 65536 + (size_t)b * 1024 + j] = f2bf(h);
    if (outy) outy[(size_t)b * 131072 + (size_t)t * 1024 + j] = h;
    if (t == 127) { hT[b * 1024 + j] = h; cT[b * 1024 + j] = c; }
    if (t != 127) gridbar(bar, phase_base + (unsigned int)t + 1u);  // last step: kernel boundary flushes
  }
}

// ---------------- launch ----------------
extern "C" void kernel_launch(void* const* d_in, const int* in_sizes, int n_in,
                              void* d_out, int out_size, void* d_ws, size_t ws_size,
                              hipStream_t stream) {
  const int*   x    = (const int*)d_in[0];
  const float* h0_1 = (const float*)d_in[1];
  const float* c0_1 = (const float*)d_in[2];
  const float* h0_2 = (const float*)d_in[3];
  const float* c0_2 = (const float*)d_in[4];
  const float* emb  = (const float*)d_in[5];
  const float* W1   = (const float*)d_in[6];
  const float* U1   = (const float*)d_in[7];
  const float* b1   = (const float*)d_in[8];
  const float* W2   = (const float*)d_in[9];
  const float* U2   = (const float*)d_in[10];
  const float* b2   = (const float*)d_in[11];
  float* outf = (float*)d_out;

  unsigned short* ws  = (unsigned short*)d_ws;
  unsigned short* ebf = ws;                    // 2,097,152
  unsigned short* W1t = ws + 2097152;          // 1,048,576
  unsigned short* W2t = ws + 3145728;          // 4,194,304
  unsigned short* xz  = ws + 7340032;          // 33,554,432
  unsigned short* h1h = ws + 40894464;         // 8,454,144
  unsigned short* h2h = ws + 49348608;         // 8,454,144
  unsigned int*   bar = (unsigned int*)(ws + 57802752);  // 4KB barrier area

  float* hT1 = outf + 8388608;
  float* cT1 = outf + 8454144;
  float* hT2 = outf + 8519680;
  float* cT2 = outf + 8585216;

  zero_bar<<<4, 256, 0, stream>>>(bar);
  prep_e<<<1024, 256, 0, stream>>>(x, emb, ebf);
  prep_wt<<<512, 256, 0, stream>>>(W1, W1t, 256);
  prep_wt<<<2048, 256, 0, stream>>>(W2, W2t, 1024);
  prep_cvt<<<256, 256, 0, stream>>>(h0_1, h1h);
  prep_cvt<<<256, 256, 0, stream>>>(h0_2, h2h);

  gemm_xz<<<dim3(64, 32), 256, 0, stream>>>(ebf, W1t, b1, xz, 256);

  {
    const float* Uc = U1; const unsigned short* xzc = xz; unsigned short* hh = h1h;
    const float* c0c = c0_1; float* oy = nullptr; float* ht = hT1; float* ct = cT1;
    unsigned int* brc = bar; unsigned int pb = 0u;
    void* args[] = {&Uc, &xzc, &hh, &c0c, &oy, &ht, &ct, &brc, &pb};
    hipLaunchCooperativeKernel((void*)lstm_recur, dim3(256), dim3(256), args, 0, stream);
  }

  gemm_xz<<<dim3(64, 32), 256, 0, stream>>>(h1h + 65536, W2t, b2, xz, 1024);

  {
    const float* Uc = U2; const unsigned short* xzc = xz; unsigned short* hh = h2h;
    const float* c0c = c0_2; float* oy = outf; float* ht = hT2; float* ct = cT2;
    unsigned int* brc = bar; unsigned int pb = 1000u;
    void* args[] = {&Uc, &xzc, &hh, &c0c, &oy, &ht, &ct, &brc, &pb};
    hipLaunchCooperativeKernel((void*)lstm_recur, dim3(256), dim3(256), args, 0, stream);
  }
}

// Round 4
// 1982.235 us; speedup vs baseline: 4.5765x; 1.5704x over previous
//
#include <hip/hip_runtime.h>

typedef __attribute__((ext_vector_type(8))) short short8;
typedef __attribute__((ext_vector_type(4))) float floatx4;

#define GLOBAL_AS __attribute__((address_space(1)))
#define LDS_AS    __attribute__((address_space(3)))

__device__ __forceinline__ float bf2f(unsigned short u) {
  union { float f; unsigned int i; } v; v.i = ((unsigned int)u) << 16; return v.f;
}
__device__ __forceinline__ unsigned short f2bf(float f) {
  union { float f; unsigned int i; } v; v.f = f;
  unsigned int r = (v.i + 0x7fffu + ((v.i >> 16) & 1u)) >> 16;
  return (unsigned short)r;
}
__device__ __forceinline__ float sigm(float x) { return 1.0f / (1.0f + __expf(-x)); }
__device__ __forceinline__ float tanh_f(float x) { return 2.0f * sigm(2.0f * x) - 1.0f; }

// write-through 2B store: bypasses/doesn't-allocate L2, lands at LLC (coherence point).
__device__ __forceinline__ void llc_store_u16(unsigned short* p, unsigned short v) {
  unsigned int v32 = v;
  asm volatile("global_store_short %0, %1, off sc0 sc1" :: "v"(p), "v"(v32) : "memory");
}

// ---------------- atomic-free, FENCE-FREE grid barrier ----------------
// Correctness: h communication uses rotating slabs (each slab written once, read
// only after its write), producer stores are write-through-to-LLC, caches start
// clean at dispatch -> no stale line can exist. Flags/gen are agent-scope
// atomics (LLC-resident). So no buffer_wbl2 / buffer_inv needed at all.
__device__ __forceinline__ void gridbar(unsigned int* bar, unsigned int phase) {
  __syncthreads();                      // compiler emits vmcnt(0) drain before s_barrier
  unsigned int* flags = bar;
  unsigned int* gen = bar + 512;
  if (threadIdx.x == 0) {
    __hip_atomic_store(&flags[blockIdx.x], phase, __ATOMIC_RELAXED, __HIP_MEMORY_SCOPE_AGENT);
  }
  asm volatile("" ::: "memory");
  if (blockIdx.x == 0) {
    unsigned int v;
    do {
      v = __hip_atomic_load(&flags[threadIdx.x], __ATOMIC_RELAXED, __HIP_MEMORY_SCOPE_AGENT);
      if (v < phase) __builtin_amdgcn_s_sleep(1);
    } while (v < phase);
    __syncthreads();
    if (threadIdx.x == 0)
      __hip_atomic_store(gen, phase, __ATOMIC_RELAXED, __HIP_MEMORY_SCOPE_AGENT);
  }
  if (threadIdx.x == 0) {
    while (__hip_atomic_load(gen, __ATOMIC_RELAXED, __HIP_MEMORY_SCOPE_AGENT) < phase)
      __builtin_amdgcn_s_sleep(1);
  }
  asm volatile("" ::: "memory");        // no load hoisting above the poll
  __syncthreads();
}

__global__ void zero_bar(unsigned int* bar) {
  int i = blockIdx.x * 256 + threadIdx.x;
  if (i < 1024) bar[i] = 0u;
}

// ---------------- prep kernels ----------------

__global__ void prep_e(const int* __restrict__ x, const float* __restrict__ emb,
                       unsigned short* __restrict__ ebf) {
  int idx = blockIdx.x * 256 + threadIdx.x;   // [0, 8192*32)
  int koct = idx & 31;
  int m = idx >> 5;
  int t = m >> 6, b = m & 63;
  int tok = x[b * 128 + t];
  const float* src = emb + (size_t)tok * 256 + (size_t)koct * 8;
  short8 v;
#pragma unroll
  for (int j = 0; j < 8; ++j) v[j] = (short)f2bf(src[j]);
  *(short8*)(ebf + (size_t)m * 256 + koct * 8) = v;
}

__global__ void prep_wt(const float* __restrict__ W, unsigned short* __restrict__ Wt, int K) {
  int idx = blockIdx.x * 256 + threadIdx.x;   // [0, 4096*(K/8))
  int n = idx & 4095;
  int koct = idx >> 12;
  short8 v;
#pragma unroll
  for (int j = 0; j < 8; ++j) v[j] = (short)f2bf(W[(size_t)(koct * 8 + j) * 4096 + n]);
  *(short8*)(Wt + (size_t)n * K + koct * 8) = v;
}

__global__ void prep_cvt(const float* __restrict__ s, unsigned short* __restrict__ d) {
  int i = blockIdx.x * 256 + threadIdx.x;
  d[i] = f2bf(s[i]);
}

// ---------------- GEMM: xz = A @ Bt^T + bias, block-sliced bf16 output ----------------
__global__ __launch_bounds__(256) void gemm_xz(
    const unsigned short* __restrict__ A,
    const unsigned short* __restrict__ Bt,
    const float* __restrict__ bias,
    unsigned short* __restrict__ xz, int K) {
  __shared__ __align__(16) unsigned short Alds[128 * 32];
  __shared__ __align__(16) unsigned short Blds[128 * 32];
  const int tid = threadIdx.x;
  const int w = tid >> 6, l = tid & 63;
  const int m0 = blockIdx.x * 128;
  const int n0 = blockIdx.y * 128;
  const int mw = (w >> 1) * 64, nw = (w & 1) * 64;
  floatx4 acc[4][4];
#pragma unroll
  for (int i = 0; i < 4; ++i)
#pragma unroll
    for (int jq = 0; jq < 4; ++jq) acc[i][jq] = (floatx4){0.f, 0.f, 0.f, 0.f};

  const int ktiles = K >> 5;
  for (int kt = 0; kt < ktiles; ++kt) {
#pragma unroll
    for (int i = 0; i < 2; ++i) {
      int off = (w * 2 + i) * 1024 + l * 16;
      int row = off >> 6, colb = off & 63;
      const char* gA = (const char*)A + ((size_t)(m0 + row) * K) * 2 + (size_t)kt * 64 + colb;
      __builtin_amdgcn_global_load_lds((const GLOBAL_AS void*)gA,
                                       (LDS_AS void*)((char*)Alds + off), 16, 0, 0);
      const char* gB = (const char*)Bt + ((size_t)(n0 + row) * K) * 2 + (size_t)kt * 64 + colb;
      __builtin_amdgcn_global_load_lds((const GLOBAL_AS void*)gB,
                                       (LDS_AS void*)((char*)Blds + off), 16, 0, 0);
    }
    __syncthreads();
    short8 af[4], bfr[4];
#pragma unroll
    for (int s = 0; s < 4; ++s) {
      af[s]  = *(const short8*)&Alds[(mw + s * 16 + (l & 15)) * 32 + (l >> 4) * 8];
      bfr[s] = *(const short8*)&Blds[(nw + s * 16 + (l & 15)) * 32 + (l >> 4) * 8];
    }
#pragma unroll
    for (int si = 0; si < 4; ++si)
#pragma unroll
      for (int sj = 0; sj < 4; ++sj)
        acc[si][sj] = __builtin_amdgcn_mfma_f32_16x16x32_bf16(af[si], bfr[sj], acc[si][sj], 0, 0, 0);
    __syncthreads();
  }
#pragma unroll
  for (int sj = 0; sj < 4; ++sj) {
    const int n = n0 + nw + sj * 16 + (l & 15);
    const float bv = bias[n];
    const int gate = n >> 10;
    const int bidx = (n & 1023) >> 2;
    const int jjj = n & 3;
#pragma unroll
    for (int si = 0; si < 4; ++si) {
#pragma unroll
      for (int r = 0; r < 4; ++r) {
        const int m = m0 + mw + si * 16 + ((l >> 4) << 2) + r;
        const int t = m >> 6, b = m & 63;
        xz[(size_t)t * 262144 + (size_t)bidx * 1024 + b * 16 + jjj * 4 + gate] =
            f2bf(acc[si][sj][r] + bv);
      }
    }
  }
}

// ---------------- cooperative LSTM recurrence (fence-free) ----------------
__global__ __launch_bounds__(256) void lstm_recur(
    const float* __restrict__ U,          // [1024][4096] fp32
    const unsigned short* __restrict__ xz,
    unsigned short* __restrict__ hhist,   // [129][64][1024] bf16, slab 0 prefilled
    const float* __restrict__ c0,         // [64][1024]
    float* __restrict__ outy,             // [64][128][1024] fp32 or nullptr
    float* __restrict__ hT,
    float* __restrict__ cT,
    unsigned int* __restrict__ bar,
    unsigned int phase_base) {
  __shared__ __align__(16) unsigned short Ulds[32 * 64 * 8]; // 32KB, [ks][lane][8]
  const int bid = blockIdx.x;
  const int tid = threadIdx.x;
  const int w = tid >> 6, l = tid & 63;

  for (int run = tid; run < 2048; run += 256) {
    const int ll = run & 63;
    const int ks = run >> 6;
    const int m = ll & 15;
    const int jjp = m >> 2, gate = m & 3;
    const int n = gate * 1024 + bid * 4 + jjp;
    const int kb = ks * 32 + (ll >> 4) * 8;
    short8 v;
#pragma unroll
    for (int jq = 0; jq < 8; ++jq) v[jq] = (short)f2bf(U[(size_t)(kb + jq) * 4096 + n]);
    *(short8*)&Ulds[(size_t)run * 8] = v;
  }
  __syncthreads();

  const int b = w * 16 + (l & 15);
  const int jj = l >> 4;
  const int j = bid * 4 + jj;
  float c = c0[b * 1024 + j];
  const int kq = (l >> 4) * 8;

  for (int t = 0; t < 128; ++t) {
    const unsigned short* hrow = hhist + (size_t)t * 65536 + (size_t)b * 1024;
    floatx4 a0 = {0.f, 0.f, 0.f, 0.f}, a1 = a0, a2 = a0, a3 = a0;
#pragma unroll 2
    for (int ks = 0; ks < 32; ks += 4) {
      short8 u0 = *(const short8*)&Ulds[((ks + 0) * 64 + l) * 8];
      short8 u1 = *(const short8*)&Ulds[((ks + 1) * 64 + l) * 8];
      short8 u2 = *(const short8*)&Ulds[((ks + 2) * 64 + l) * 8];
      short8 u3 = *(const short8*)&Ulds[((ks + 3) * 64 + l) * 8];
      short8 hv0 = *(const short8*)&hrow[(ks + 0) * 32 + kq];
      short8 hv1 = *(const short8*)&hrow[(ks + 1) * 32 + kq];
      short8 hv2 = *(const short8*)&hrow[(ks + 2) * 32 + kq];
      short8 hv3 = *(const short8*)&hrow[(ks + 3) * 32 + kq];
      a0 = __builtin_amdgcn_mfma_f32_16x16x32_bf16(u0, hv0, a0, 0, 0, 0);
      a1 = __builtin_amdgcn_mfma_f32_16x16x32_bf16(u1, hv1, a1, 0, 0, 0);
      a2 = __builtin_amdgcn_mfma_f32_16x16x32_bf16(u2, hv2, a2, 0, 0, 0);
      a3 = __builtin_amdgcn_mfma_f32_16x16x32_bf16(u3, hv3, a3, 0, 0, 0);
    }
    floatx4 acc = (a0 + a1) + (a2 + a3);
    const unsigned short* xzp = xz + (size_t)t * 262144 + (size_t)bid * 1024 + b * 16 + jj * 4;
    ushort4 xv = *(const ushort4*)xzp;
    float zi = acc[0] + bf2f(xv.x);
    float zf = acc[1] + bf2f(xv.y);
    float zg = acc[2] + bf2f(xv.z);
    float zo = acc[3] + bf2f(xv.w);
    float ig = sigm(zi), fg = sigm(zf), gg = tanh_f(zg), og = sigm(zo);
    c = fg * c + ig * gg;
    float h = og * tanh_f(c);
    // write-through to LLC: next step's readers fetch fresh lines (rotating slab)
    llc_store_u16(hhist + (size_t)(t + 1) * 65536 + (size_t)b * 1024 + j, f2bf(h));
    if (outy) outy[(size_t)b * 131072 + (size_t)t * 1024 + j] = h;
    if (t == 127) { hT[b * 1024 + j] = h; cT[b * 1024 + j] = c; }
    if (t != 127) gridbar(bar, phase_base + (unsigned int)t + 1u);  // last step: kernel boundary flushes
  }
}

// ---------------- launch ----------------
extern "C" void kernel_launch(void* const* d_in, const int* in_sizes, int n_in,
                              void* d_out, int out_size, void* d_ws, size_t ws_size,
                              hipStream_t stream) {
  const int*   x    = (const int*)d_in[0];
  const float* h0_1 = (const float*)d_in[1];
  const float* c0_1 = (const float*)d_in[2];
  const float* h0_2 = (const float*)d_in[3];
  const float* c0_2 = (const float*)d_in[4];
  const float* emb  = (const float*)d_in[5];
  const float* W1   = (const float*)d_in[6];
  const float* U1   = (const float*)d_in[7];
  const float* b1   = (const float*)d_in[8];
  const float* W2   = (const float*)d_in[9];
  const float* U2   = (const float*)d_in[10];
  const float* b2   = (const float*)d_in[11];
  float* outf = (float*)d_out;

  unsigned short* ws  = (unsigned short*)d_ws;
  unsigned short* ebf = ws;                    // 2,097,152
  unsigned short* W1t = ws + 2097152;          // 1,048,576
  unsigned short* W2t = ws + 3145728;          // 4,194,304
  unsigned short* xz  = ws + 7340032;          // 33,554,432
  unsigned short* h1h = ws + 40894464;         // 8,454,144
  unsigned short* h2h = ws + 49348608;         // 8,454,144
  unsigned int*   bar = (unsigned int*)(ws + 57802752);  // 4KB barrier area

  float* hT1 = outf + 8388608;
  float* cT1 = outf + 8454144;
  float* hT2 = outf + 8519680;
  float* cT2 = outf + 8585216;

  zero_bar<<<4, 256, 0, stream>>>(bar);
  prep_e<<<1024, 256, 0, stream>>>(x, emb, ebf);
  prep_wt<<<512, 256, 0, stream>>>(W1, W1t, 256);
  prep_wt<<<2048, 256, 0, stream>>>(W2, W2t, 1024);
  prep_cvt<<<256, 256, 0, stream>>>(h0_1, h1h);
  prep_cvt<<<256, 256, 0, stream>>>(h0_2, h2h);

  gemm_xz<<<dim3(64, 32), 256, 0, stream>>>(ebf, W1t, b1, xz, 256);

  {
    const float* Uc = U1; const unsigned short* xzc = xz; unsigned short* hh = h1h;
    const float* c0c = c0_1; float* oy = nullptr; float* ht = hT1; float* ct = cT1;
    unsigned int* brc = bar; unsigned int pb = 0u;
    void* args[] = {&Uc, &xzc, &hh, &c0c, &oy, &ht, &ct, &brc, &pb};
    hipLaunchCooperativeKernel((void*)lstm_recur, dim3(256), dim3(256), args, 0, stream);
  }

  gemm_xz<<<dim3(64, 32), 256, 0, stream>>>(h1h + 65536, W2t, b2, xz, 1024);

  {
    const float* Uc = U2; const unsigned short* xzc = xz; unsigned short* hh = h2h;
    const float* c0c = c0_2; float* oy = outf; float* ht = hT2; float* ct = cT2;
    unsigned int* brc = bar; unsigned int pb = 1000u;
    void* args[] = {&Uc, &xzc, &hh, &c0c, &oy, &ht, &ct, &brc, &pb};
    hipLaunchCooperativeKernel((void*)lstm_recur, dim3(256), dim3(256), args, 0, stream);
  }
}

// Round 5
// 1859.340 us; speedup vs baseline: 4.8790x; 1.0661x over previous
//
#include <hip/hip_runtime.h>

typedef __attribute__((ext_vector_type(8))) short short8;
typedef __attribute__((ext_vector_type(4))) float floatx4;

#define MFMA16(a, b, acc) __builtin_amdgcn_mfma_f32_16x16x32_bf16((a), (b), (acc), 0, 0, 0)

__device__ __forceinline__ float bf2f(unsigned short u) {
  union { float f; unsigned int i; } v; v.i = ((unsigned int)u) << 16; return v.f;
}
__device__ __forceinline__ unsigned short f2bf(float f) {
  union { float f; unsigned int i; } v; v.f = f;
  unsigned int r = (v.i + 0x7fffu + ((v.i >> 16) & 1u)) >> 16;
  return (unsigned short)r;
}
__device__ __forceinline__ float sigm(float x) { return 1.0f / (1.0f + __expf(-x)); }
__device__ __forceinline__ float tanh_f(float x) { return 2.0f * sigm(2.0f * x) - 1.0f; }

// write-through 2B store: no L2 allocation, lands at LLC (coherence point)
__device__ __forceinline__ void llc_store_u16(unsigned short* p, unsigned short v) {
  unsigned int v32 = v;
  asm volatile("global_store_short %0, %1, off sc0 sc1" :: "v"(p), "v"(v32) : "memory");
}

// ---------------- flat all-poll grid barrier (no checker, no gen, no fences) ----
// Every block stores its own flag (after syncthreads -> all its stores drained);
// every thread polls one flag; block proceeds when its 256 threads each saw
// their flag reach `phase` (=> all 256 blocks arrived). Critical path: one
// flag-store + one poll-notice (~2 LLC hops). Rotating-slab h + write-through
// stores make cache maintenance unnecessary (see round-4 analysis).
__device__ __forceinline__ void gridbar(unsigned int* bar, unsigned int phase) {
  __syncthreads();                     // drains this block's stores (vmcnt 0)
  if (threadIdx.x == 0)
    __hip_atomic_store(&bar[blockIdx.x], phase, __ATOMIC_RELAXED, __HIP_MEMORY_SCOPE_AGENT);
  asm volatile("" ::: "memory");
  while (__hip_atomic_load(&bar[threadIdx.x], __ATOMIC_RELAXED, __HIP_MEMORY_SCOPE_AGENT) < phase)
    __builtin_amdgcn_s_sleep(1);
  asm volatile("" ::: "memory");       // no load hoisting above the poll
  __syncthreads();
}

__global__ void zero_bar(unsigned int* bar) {
  int i = blockIdx.x * 256 + threadIdx.x;
  if (i < 1024) bar[i] = 0u;
}

// ---------------- prep kernels ----------------

// ebf[m=t*64+b][k] = bf16(emb[x[b][t]][k])
__global__ void prep_e(const int* __restrict__ x, const float* __restrict__ emb,
                       unsigned short* __restrict__ ebf) {
  int idx = blockIdx.x * 256 + threadIdx.x;   // [0, 8192*32)
  int koct = idx & 31;
  int m = idx >> 5;
  int t = m >> 6, b = m & 63;
  int tok = x[b * 128 + t];
  const float* src = emb + (size_t)tok * 256 + (size_t)koct * 8;
  short8 v;
#pragma unroll
  for (int j = 0; j < 8; ++j) v[j] = (short)f2bf(src[j]);
  *(short8*)(ebf + (size_t)m * 256 + koct * 8) = v;
}

// Wt[n][k] = bf16(W[k][n]); W is [K][4096]
__global__ void prep_wt(const float* __restrict__ W, unsigned short* __restrict__ Wt, int K) {
  int idx = blockIdx.x * 256 + threadIdx.x;   // [0, 4096*(K/8))
  int n = idx & 4095;
  int koct = idx >> 12;
  short8 v;
#pragma unroll
  for (int j = 0; j < 8; ++j) v[j] = (short)f2bf(W[(size_t)(koct * 8 + j) * 4096 + n]);
  *(short8*)(Wt + (size_t)n * K + koct * 8) = v;
}

__global__ void prep_cvt(const float* __restrict__ s, unsigned short* __restrict__ d) {
  int i = blockIdx.x * 256 + threadIdx.x;
  d[i] = f2bf(s[i]);
}

// ---------------- fused two-layer LSTM (one cooperative dispatch) ----------------
// Block bid owns j-quad = bid*4..bid*4+3 for BOTH layers. Super-step s:
//   layer-1 computes y1[s]   from e[s], h1 state (=h1h slab s)     [s<128]
//   layer-2 computes out[s-1] from y1[s-1] (=h1h slab s, SAME row loads)
//            and h2 state (=h2h slab s-1)                          [s>=1]
// One barrier per super-step: 128 total (vs 254 in the split design).
__global__ __launch_bounds__(256) void lstm_fused(
    const unsigned short* __restrict__ W1t,  // [4096][256]  bf16
    const unsigned short* __restrict__ U1t,  // [4096][1024] bf16
    const unsigned short* __restrict__ W2t,  // [4096][1024] bf16
    const unsigned short* __restrict__ U2t,  // [4096][1024] bf16
    const unsigned short* __restrict__ ebf,  // [8192][256]  bf16
    unsigned short* __restrict__ h1h,        // [129][64][1024], slab 0 prefilled
    unsigned short* __restrict__ h2h,        // [129][64][1024], slab 0 prefilled
    const float* __restrict__ c0_1, const float* __restrict__ c0_2,
    const float* __restrict__ b1,   const float* __restrict__ b2,
    float* __restrict__ outy,                 // [64][128][1024]
    float* __restrict__ hT1, float* __restrict__ cT1,
    float* __restrict__ hT2, float* __restrict__ cT2,
    unsigned int* __restrict__ bar) {
  extern __shared__ __align__(16) unsigned short lds[];   // 104 KB
  unsigned short* U1l = lds;             // 16384 ush (32 KB)
  unsigned short* W2l = lds + 16384;     // 32 KB
  unsigned short* U2l = lds + 32768;     // 32 KB
  unsigned short* W1l = lds + 49152;     // 8 KB
  const int bid = blockIdx.x, tid = threadIdx.x;
  const int w = tid >> 6, l = tid & 63;

  // stage A-fragments from n-major bf16 arrays; each wave reads 16 full 64B lines
  for (int run = tid; run < 2048; run += 256) {
    int ll = run & 63, ks = run >> 6;
    int m = ll & 15;
    int n = (m & 3) * 1024 + bid * 4 + (m >> 2);
    int kb = ks * 32 + (ll >> 4) * 8;
    *(short8*)&U1l[run * 8] = *(const short8*)&U1t[(size_t)n * 1024 + kb];
    *(short8*)&W2l[run * 8] = *(const short8*)&W2t[(size_t)n * 1024 + kb];
    *(short8*)&U2l[run * 8] = *(const short8*)&U2t[(size_t)n * 1024 + kb];
  }
  for (int run = tid; run < 512; run += 256) {
    int ll = run & 63, ks = run >> 6;
    int m = ll & 15;
    int n = (m & 3) * 1024 + bid * 4 + (m >> 2);
    int kb = ks * 32 + (ll >> 4) * 8;
    *(short8*)&W1l[run * 8] = *(const short8*)&W1t[(size_t)n * 256 + kb];
  }
  __syncthreads();

  const int b = w * 16 + (l & 15);
  const int jj = l >> 4;
  const int j = bid * 4 + jj;
  const int kq = jj * 8;
  float c1 = c0_1[b * 1024 + j];
  float c2 = c0_2[b * 1024 + j];
  float b1r[4], b2r[4];
#pragma unroll
  for (int g = 0; g < 4; ++g) { b1r[g] = b1[g * 1024 + j]; b2r[g] = b2[g * 1024 + j]; }

  // ---- s = 0: layer-1 only ----
  {
    const unsigned short* er = ebf + ((size_t)b << 8);        // t=0 row
    const unsigned short* h1row = h1h + (size_t)b * 1024;     // slab 0
    floatx4 a1a = {0.f, 0.f, 0.f, 0.f}, a1b = a1a;
#pragma unroll
    for (int ks = 0; ks < 8; ++ks) {
      short8 ev = *(const short8*)&er[ks * 32 + kq];
      short8 w1 = *(const short8*)&W1l[(ks * 64 + l) * 8];
      if (ks & 1) a1b = MFMA16(w1, ev, a1b); else a1a = MFMA16(w1, ev, a1a);
    }
#pragma unroll 4
    for (int ks = 0; ks < 32; ++ks) {
      short8 hv = *(const short8*)&h1row[ks * 32 + kq];
      short8 u1 = *(const short8*)&U1l[(ks * 64 + l) * 8];
      if (ks & 1) a1b = MFMA16(u1, hv, a1b); else a1a = MFMA16(u1, hv, a1a);
    }
    floatx4 z1 = a1a + a1b;
    float ig = sigm(z1[0] + b1r[0]), fg = sigm(z1[1] + b1r[1]);
    float gg = tanh_f(z1[2] + b1r[2]), og = sigm(z1[3] + b1r[3]);
    c1 = fg * c1 + ig * gg;
    float h = og * tanh_f(c1);
    llc_store_u16(h1h + 65536 + (size_t)b * 1024 + j, f2bf(h));
    gridbar(bar, 1u);
  }

  // ---- s = 1..127: both layers ----
  for (int s = 1; s < 128; ++s) {
    const unsigned short* er = ebf + ((size_t)(s * 64 + b) << 8);
    const unsigned short* h1row = h1h + (size_t)s * 65536 + (size_t)b * 1024;
    const unsigned short* h2row = h2h + (size_t)(s - 1) * 65536 + (size_t)b * 1024;
    floatx4 a1a = {0.f, 0.f, 0.f, 0.f}, a1b = a1a, a2a = a1a, a2b = a1a;
#pragma unroll
    for (int ks = 0; ks < 8; ++ks) {
      short8 ev = *(const short8*)&er[ks * 32 + kq];
      short8 w1 = *(const short8*)&W1l[(ks * 64 + l) * 8];
      if (ks & 1) a1b = MFMA16(w1, ev, a1b); else a1a = MFMA16(w1, ev, a1a);
    }
#pragma unroll 4
    for (int ks = 0; ks < 32; ++ks) {
      short8 hv  = *(const short8*)&h1row[ks * 32 + kq];   // y1[s-1] AND h1-state
      short8 h2v = *(const short8*)&h2row[ks * 32 + kq];
      short8 u1 = *(const short8*)&U1l[(ks * 64 + l) * 8];
      short8 w2 = *(const short8*)&W2l[(ks * 64 + l) * 8];
      short8 u2 = *(const short8*)&U2l[(ks * 64 + l) * 8];
      if (ks & 1) a1b = MFMA16(u1, hv, a1b); else a1a = MFMA16(u1, hv, a1a);
      a2a = MFMA16(w2, hv, a2a);
      a2b = MFMA16(u2, h2v, a2b);
    }
    floatx4 z1 = a1a + a1b, z2 = a2a + a2b;
    {
      float ig = sigm(z1[0] + b1r[0]), fg = sigm(z1[1] + b1r[1]);
      float gg = tanh_f(z1[2] + b1r[2]), og = sigm(z1[3] + b1r[3]);
      c1 = fg * c1 + ig * gg;
      float h = og * tanh_f(c1);
      llc_store_u16(h1h + (size_t)(s + 1) * 65536 + (size_t)b * 1024 + j, f2bf(h));
      if (s == 127) { hT1[b * 1024 + j] = h; cT1[b * 1024 + j] = c1; }
    }
    {
      float ig = sigm(z2[0] + b2r[0]), fg = sigm(z2[1] + b2r[1]);
      float gg = tanh_f(z2[2] + b2r[2]), og = sigm(z2[3] + b2r[3]);
      c2 = fg * c2 + ig * gg;
      float h = og * tanh_f(c2);
      llc_store_u16(h2h + (size_t)s * 65536 + (size_t)b * 1024 + j, f2bf(h));
      outy[(size_t)b * 131072 + (size_t)(s - 1) * 1024 + j] = h;
    }
    gridbar(bar, (unsigned int)(s + 1));
  }

  // ---- s = 128: layer-2 only ----
  {
    const unsigned short* h1row = h1h + (size_t)128 * 65536 + (size_t)b * 1024;
    const unsigned short* h2row = h2h + (size_t)127 * 65536 + (size_t)b * 1024;
    floatx4 a2a = {0.f, 0.f, 0.f, 0.f}, a2b = a2a;
#pragma unroll 4
    for (int ks = 0; ks < 32; ++ks) {
      short8 hv  = *(const short8*)&h1row[ks * 32 + kq];
      short8 h2v = *(const short8*)&h2row[ks * 32 + kq];
      short8 w2 = *(const short8*)&W2l[(ks * 64 + l) * 8];
      short8 u2 = *(const short8*)&U2l[(ks * 64 + l) * 8];
      a2a = MFMA16(w2, hv, a2a);
      a2b = MFMA16(u2, h2v, a2b);
    }
    floatx4 z2 = a2a + a2b;
    float ig = sigm(z2[0] + b2r[0]), fg = sigm(z2[1] + b2r[1]);
    float gg = tanh_f(z2[2] + b2r[2]), og = sigm(z2[3] + b2r[3]);
    c2 = fg * c2 + ig * gg;
    float h = og * tanh_f(c2);
    outy[(size_t)b * 131072 + (size_t)127 * 1024 + j] = h;
    hT2[b * 1024 + j] = h;
    cT2[b * 1024 + j] = c2;
  }
}

// ---------------- launch ----------------
extern "C" void kernel_launch(void* const* d_in, const int* in_sizes, int n_in,
                              void* d_out, int out_size, void* d_ws, size_t ws_size,
                              hipStream_t stream) {
  const int*   x    = (const int*)d_in[0];
  const float* h0_1 = (const float*)d_in[1];
  const float* c0_1 = (const float*)d_in[2];
  const float* h0_2 = (const float*)d_in[3];
  const float* c0_2 = (const float*)d_in[4];
  const float* emb  = (const float*)d_in[5];
  const float* W1   = (const float*)d_in[6];
  const float* U1   = (const float*)d_in[7];
  const float* b1   = (const float*)d_in[8];
  const float* W2   = (const float*)d_in[9];
  const float* U2   = (const float*)d_in[10];
  const float* b2   = (const float*)d_in[11];
  float* outf = (float*)d_out;

  unsigned short* ws  = (unsigned short*)d_ws;
  unsigned short* ebf = ws;                    //  2,097,152 ush
  unsigned short* W1t = ws +  2097152;         //  1,048,576
  unsigned short* U1t = ws +  3145728;         //  4,194,304
  unsigned short* W2t = ws +  7340032;         //  4,194,304
  unsigned short* U2t = ws + 11534336;         //  4,194,304
  unsigned short* h1h = ws + 15728640;         //  8,454,144
  unsigned short* h2h = ws + 24182784;         //  8,454,144
  unsigned int*   bar = (unsigned int*)(ws + 32636928);  // 4 KB (total ~65.3 MB)

  float* hT1 = outf + 8388608;
  float* cT1 = outf + 8454144;
  float* hT2 = outf + 8519680;
  float* cT2 = outf + 8585216;

  zero_bar<<<4, 256, 0, stream>>>(bar);
  prep_e<<<1024, 256, 0, stream>>>(x, emb, ebf);
  prep_wt<<<512,  256, 0, stream>>>(W1, W1t, 256);
  prep_wt<<<2048, 256, 0, stream>>>(U1, U1t, 1024);
  prep_wt<<<2048, 256, 0, stream>>>(W2, W2t, 1024);
  prep_wt<<<2048, 256, 0, stream>>>(U2, U2t, 1024);
  prep_cvt<<<256, 256, 0, stream>>>(h0_1, h1h);
  prep_cvt<<<256, 256, 0, stream>>>(h0_2, h2h);

  // allow 104 KB dynamic LDS (gfx950 has 160 KB/CU)
  static bool attr_done = false;
  if (!attr_done) {
    (void)hipFuncSetAttribute((const void*)lstm_fused,
                              hipFuncAttributeMaxDynamicSharedMemorySize, 106496);
    attr_done = true;
  }

  {
    const unsigned short *w1c = W1t, *u1c = U1t, *w2c = W2t, *u2c = U2t, *ec = ebf;
    unsigned short *h1c = h1h, *h2c = h2h;
    const float *c01 = c0_1, *c02 = c0_2, *b1c = b1, *b2c = b2;
    float *oy = outf, *ht1 = hT1, *ct1 = cT1, *ht2 = hT2, *ct2 = cT2;
    unsigned int* brc = bar;
    void* args[] = {&w1c, &u1c, &w2c, &u2c, &ec, &h1c, &h2c,
                    &c01, &c02, &b1c, &b2c, &oy, &ht1, &ct1, &ht2, &ct2, &brc};
    hipLaunchCooperativeKernel((void*)lstm_fused, dim3(256), dim3(256), args, 106496, stream);
  }
}

// Round 6
// 1583.600 us; speedup vs baseline: 5.7285x; 1.1741x over previous
//
#include <hip/hip_runtime.h>

typedef __attribute__((ext_vector_type(8))) short short8;
typedef __attribute__((ext_vector_type(4))) float floatx4;

#define MFMA16(a, b, acc) __builtin_amdgcn_mfma_f32_16x16x32_bf16((a), (b), (acc), 0, 0, 0)

__device__ __forceinline__ float bf2f(unsigned short u) {
  union { float f; unsigned int i; } v; v.i = ((unsigned int)u) << 16; return v.f;
}
__device__ __forceinline__ unsigned short f2bf(float f) {
  union { float f; unsigned int i; } v; v.f = f;
  unsigned int r = (v.i + 0x7fffu + ((v.i >> 16) & 1u)) >> 16;
  return (unsigned short)r;
}
__device__ __forceinline__ float sigm(float x) { return 1.0f / (1.0f + __expf(-x)); }
__device__ __forceinline__ float tanh_f(float x) { return 2.0f * sigm(2.0f * x) - 1.0f; }

// write-through 2B store: no L2 allocation, lands at LLC (coherence point)
__device__ __forceinline__ void llc_store_u16(unsigned short* p, unsigned short v) {
  unsigned int v32 = v;
  asm volatile("global_store_short %0, %1, off sc0 sc1" :: "v"(p), "v"(v32) : "memory");
}

// ---------------- hierarchical checker barrier (low poll traffic) ----------------
// flags[0..255] (lines 0-15) <- every block's t0.
// 8 leaders (bid%32==0): wave0 polls its group's 32 flags -> gflags[g] (line 16+).
// root (bid 0): polls gflags[0..7] -> gen (line 32).
// everyone: t0 polls gen. ~3 serialized poll-notice hops, minimal line contention.
// Fence-free: rotating h slabs + write-through producer stores (see R4 analysis).
__device__ __forceinline__ void gridbar(unsigned int* bar, unsigned int phase) {
  __syncthreads();                     // compiler emits vmcnt(0) drain before s_barrier
  const unsigned int bid = blockIdx.x;
  const unsigned int tid = threadIdx.x;
  unsigned int* flags  = bar;          // 256 dwords
  unsigned int* gflags = bar + 256;    // 8 dwords (line 16)
  unsigned int* gen    = bar + 512;    // line 32
  if (tid == 0)
    __hip_atomic_store(&flags[bid], phase, __ATOMIC_RELAXED, __HIP_MEMORY_SCOPE_AGENT);
  asm volatile("" ::: "memory");
  if ((bid & 31u) == 0u && tid < 64) {         // leader wave
    const unsigned int g = bid >> 5;
    unsigned int v;
    do {
      v = __hip_atomic_load(&flags[g * 32 + (tid & 31)], __ATOMIC_RELAXED, __HIP_MEMORY_SCOPE_AGENT);
      if (v < phase) __builtin_amdgcn_s_sleep(1);
    } while (__all(v >= phase) == 0);
    if (tid == 0)
      __hip_atomic_store(&gflags[g], phase, __ATOMIC_RELAXED, __HIP_MEMORY_SCOPE_AGENT);
    if (bid == 0) {                            // root
      unsigned int gv;
      do {
        gv = __hip_atomic_load(&gflags[tid & 7], __ATOMIC_RELAXED, __HIP_MEMORY_SCOPE_AGENT);
        if (gv < phase) __builtin_amdgcn_s_sleep(1);
      } while (__all(gv >= phase) == 0);
      if (tid == 0)
        __hip_atomic_store(gen, phase, __ATOMIC_RELAXED, __HIP_MEMORY_SCOPE_AGENT);
    }
  }
  if (tid == 0) {
    while (__hip_atomic_load(gen, __ATOMIC_RELAXED, __HIP_MEMORY_SCOPE_AGENT) < phase)
      __builtin_amdgcn_s_sleep(1);
  }
  asm volatile("" ::: "memory");       // no load hoisting above the poll
  __syncthreads();
}

__global__ void zero_bar(unsigned int* bar) {
  int i = blockIdx.x * 256 + threadIdx.x;
  if (i < 1024) bar[i] = 0u;
}

// ---------------- prep kernels ----------------

// ebf[m=t*64+b][k] = bf16(emb[x[b][t]][k])
__global__ void prep_e(const int* __restrict__ x, const float* __restrict__ emb,
                       unsigned short* __restrict__ ebf) {
  int idx = blockIdx.x * 256 + threadIdx.x;   // [0, 8192*32)
  int koct = idx & 31;
  int m = idx >> 5;
  int t = m >> 6, b = m & 63;
  int tok = x[b * 128 + t];
  const float* src = emb + (size_t)tok * 256 + (size_t)koct * 8;
  short8 v;
#pragma unroll
  for (int j = 0; j < 8; ++j) v[j] = (short)f2bf(src[j]);
  *(short8*)(ebf + (size_t)m * 256 + koct * 8) = v;
}

// Wt[n][k] = bf16(W[k][n]); W is [K][4096]
__global__ void prep_wt(const float* __restrict__ W, unsigned short* __restrict__ Wt, int K) {
  int idx = blockIdx.x * 256 + threadIdx.x;   // [0, 4096*(K/8))
  int n = idx & 4095;
  int koct = idx >> 12;
  short8 v;
#pragma unroll
  for (int j = 0; j < 8; ++j) v[j] = (short)f2bf(W[(size_t)(koct * 8 + j) * 4096 + n]);
  *(short8*)(Wt + (size_t)n * K + koct * 8) = v;
}

__global__ void prep_cvt(const float* __restrict__ s, unsigned short* __restrict__ d) {
  int i = blockIdx.x * 256 + threadIdx.x;
  d[i] = f2bf(s[i]);
}

// ---------------- fused two-layer LSTM (one cooperative dispatch) ----------------
// Block bid owns j-quad = bid*4..bid*4+3 for BOTH layers. Super-step s:
//   layer-1: y1[s] from e[s] + h1 (slab s);  layer-2: out[s-1] from y1[s-1]
//   (= slab s, SAME loads) + h2 (slab s-1). 128 barriers total.
// All global step inputs are bulk-prefetched into registers (72x16B) before the
// MFMA loop: one exposed LLC latency instead of dozens (1 wave/SIMD -> no TLP).
__global__ __launch_bounds__(256, 1) void lstm_fused(
    const unsigned short* __restrict__ W1t,  // [4096][256]  bf16
    const unsigned short* __restrict__ U1t,  // [4096][1024] bf16
    const unsigned short* __restrict__ W2t,  // [4096][1024] bf16
    const unsigned short* __restrict__ U2t,  // [4096][1024] bf16
    const unsigned short* __restrict__ ebf,  // [8192][256]  bf16
    unsigned short* __restrict__ h1h,        // [129][64][1024], slab 0 prefilled
    unsigned short* __restrict__ h2h,        // [129][64][1024], slab 0 prefilled
    const float* __restrict__ c0_1, const float* __restrict__ c0_2,
    const float* __restrict__ b1,   const float* __restrict__ b2,
    float* __restrict__ outy,                 // [64][128][1024]
    float* __restrict__ hT1, float* __restrict__ cT1,
    float* __restrict__ hT2, float* __restrict__ cT2,
    unsigned int* __restrict__ bar) {
  extern __shared__ __align__(16) unsigned short lds[];   // 104 KB
  unsigned short* U1l = lds;             // 32 KB
  unsigned short* W2l = lds + 16384;     // 32 KB
  unsigned short* U2l = lds + 32768;     // 32 KB
  unsigned short* W1l = lds + 49152;     // 8 KB
  const int bid = blockIdx.x, tid = threadIdx.x;
  const int w = tid >> 6, l = tid & 63;

  // stage A-fragments from n-major bf16 arrays; each wave reads full 64B lines
  for (int run = tid; run < 2048; run += 256) {
    int ll = run & 63, ks = run >> 6;
    int m = ll & 15;
    int n = (m & 3) * 1024 + bid * 4 + (m >> 2);
    int kb = ks * 32 + (ll >> 4) * 8;
    *(short8*)&U1l[run * 8] = *(const short8*)&U1t[(size_t)n * 1024 + kb];
    *(short8*)&W2l[run * 8] = *(const short8*)&W2t[(size_t)n * 1024 + kb];
    *(short8*)&U2l[run * 8] = *(const short8*)&U2t[(size_t)n * 1024 + kb];
  }
  for (int run = tid; run < 512; run += 256) {
    int ll = run & 63, ks = run >> 6;
    int m = ll & 15;
    int n = (m & 3) * 1024 + bid * 4 + (m >> 2);
    int kb = ks * 32 + (ll >> 4) * 8;
    *(short8*)&W1l[run * 8] = *(const short8*)&W1t[(size_t)n * 256 + kb];
  }
  __syncthreads();

  const int b = w * 16 + (l & 15);
  const int jj = l >> 4;
  const int j = bid * 4 + jj;
  const int kq = jj * 8;
  float c1 = c0_1[b * 1024 + j];
  float c2 = c0_2[b * 1024 + j];
  float b1r[4], b2r[4];
#pragma unroll
  for (int g = 0; g < 4; ++g) { b1r[g] = b1[g * 1024 + j]; b2r[g] = b2[g * 1024 + j]; }

  // ---- s = 0: layer-1 only ----
  {
    const unsigned short* er = ebf + ((size_t)b << 8);        // t=0 row
    const unsigned short* h1row = h1h + (size_t)b * 1024;     // slab 0
    short8 ev[8], h1v[32];
#pragma unroll
    for (int k = 0; k < 8; ++k) ev[k] = *(const short8*)&er[k * 32 + kq];
#pragma unroll
    for (int ks = 0; ks < 32; ++ks) h1v[ks] = *(const short8*)&h1row[ks * 32 + kq];
    floatx4 a1a = {0.f, 0.f, 0.f, 0.f}, a1b = a1a;
#pragma unroll
    for (int k = 0; k < 8; ++k) {
      short8 w1 = *(const short8*)&W1l[(k * 64 + l) * 8];
      if (k & 1) a1b = MFMA16(w1, ev[k], a1b); else a1a = MFMA16(w1, ev[k], a1a);
    }
#pragma unroll
    for (int ks = 0; ks < 32; ++ks) {
      short8 u1 = *(const short8*)&U1l[(ks * 64 + l) * 8];
      if (ks & 1) a1b = MFMA16(u1, h1v[ks], a1b); else a1a = MFMA16(u1, h1v[ks], a1a);
    }
    floatx4 z1 = a1a + a1b;
    float ig = sigm(z1[0] + b1r[0]), fg = sigm(z1[1] + b1r[1]);
    float gg = tanh_f(z1[2] + b1r[2]), og = sigm(z1[3] + b1r[3]);
    c1 = fg * c1 + ig * gg;
    float h = og * tanh_f(c1);
    llc_store_u16(h1h + 65536 + (size_t)b * 1024 + j, f2bf(h));
    gridbar(bar, 1u);
  }

  // ---- s = 1..127: both layers ----
  for (int s = 1; s < 128; ++s) {
    const unsigned short* er = ebf + ((size_t)(s * 64 + b) << 8);
    const unsigned short* h1row = h1h + (size_t)s * 65536 + (size_t)b * 1024;
    const unsigned short* h2row = h2h + (size_t)(s - 1) * 65536 + (size_t)b * 1024;
    // bulk prefetch: issue ALL global loads for this step back-to-back
    short8 ev[8], h1v[32], h2v[32];
#pragma unroll
    for (int ks = 0; ks < 32; ++ks) h1v[ks] = *(const short8*)&h1row[ks * 32 + kq];
#pragma unroll
    for (int ks = 0; ks < 32; ++ks) h2v[ks] = *(const short8*)&h2row[ks * 32 + kq];
#pragma unroll
    for (int k = 0; k < 8; ++k) ev[k] = *(const short8*)&er[k * 32 + kq];

    floatx4 a1a = {0.f, 0.f, 0.f, 0.f}, a1b = a1a;
    floatx4 a2a = a1a, a2b = a1a, a2c = a1a, a2d = a1a;
#pragma unroll
    for (int k = 0; k < 8; ++k) {
      short8 w1 = *(const short8*)&W1l[(k * 64 + l) * 8];
      if (k & 1) a1b = MFMA16(w1, ev[k], a1b); else a1a = MFMA16(w1, ev[k], a1a);
    }
#pragma unroll
    for (int ks = 0; ks < 32; ++ks) {
      short8 u1 = *(const short8*)&U1l[(ks * 64 + l) * 8];
      short8 w2 = *(const short8*)&W2l[(ks * 64 + l) * 8];
      short8 u2 = *(const short8*)&U2l[(ks * 64 + l) * 8];
      if (ks & 1) {
        a1b = MFMA16(u1, h1v[ks], a1b);
        a2b = MFMA16(w2, h1v[ks], a2b);
        a2d = MFMA16(u2, h2v[ks], a2d);
      } else {
        a1a = MFMA16(u1, h1v[ks], a1a);
        a2a = MFMA16(w2, h1v[ks], a2a);
        a2c = MFMA16(u2, h2v[ks], a2c);
      }
    }
    floatx4 z1 = a1a + a1b, z2 = (a2a + a2b) + (a2c + a2d);
    {
      float ig = sigm(z1[0] + b1r[0]), fg = sigm(z1[1] + b1r[1]);
      float gg = tanh_f(z1[2] + b1r[2]), og = sigm(z1[3] + b1r[3]);
      c1 = fg * c1 + ig * gg;
      float h = og * tanh_f(c1);
      llc_store_u16(h1h + (size_t)(s + 1) * 65536 + (size_t)b * 1024 + j, f2bf(h));
      if (s == 127) { hT1[b * 1024 + j] = h; cT1[b * 1024 + j] = c1; }
    }
    {
      float ig = sigm(z2[0] + b2r[0]), fg = sigm(z2[1] + b2r[1]);
      float gg = tanh_f(z2[2] + b2r[2]), og = sigm(z2[3] + b2r[3]);
      c2 = fg * c2 + ig * gg;
      float h = og * tanh_f(c2);
      llc_store_u16(h2h + (size_t)s * 65536 + (size_t)b * 1024 + j, f2bf(h));
      outy[(size_t)b * 131072 + (size_t)(s - 1) * 1024 + j] = h;
    }
    gridbar(bar, (unsigned int)(s + 1));
  }

  // ---- s = 128: layer-2 only ----
  {
    const unsigned short* h1row = h1h + (size_t)128 * 65536 + (size_t)b * 1024;
    const unsigned short* h2row = h2h + (size_t)127 * 65536 + (size_t)b * 1024;
    short8 h1v[32], h2v[32];
#pragma unroll
    for (int ks = 0; ks < 32; ++ks) h1v[ks] = *(const short8*)&h1row[ks * 32 + kq];
#pragma unroll
    for (int ks = 0; ks < 32; ++ks) h2v[ks] = *(const short8*)&h2row[ks * 32 + kq];
    floatx4 a2a = {0.f, 0.f, 0.f, 0.f}, a2b = a2a, a2c = a2a, a2d = a2a;
#pragma unroll
    for (int ks = 0; ks < 32; ++ks) {
      short8 w2 = *(const short8*)&W2l[(ks * 64 + l) * 8];
      short8 u2 = *(const short8*)&U2l[(ks * 64 + l) * 8];
      if (ks & 1) { a2b = MFMA16(w2, h1v[ks], a2b); a2d = MFMA16(u2, h2v[ks], a2d); }
      else        { a2a = MFMA16(w2, h1v[ks], a2a); a2c = MFMA16(u2, h2v[ks], a2c); }
    }
    floatx4 z2 = (a2a + a2b) + (a2c + a2d);
    float ig = sigm(z2[0] + b2r[0]), fg = sigm(z2[1] + b2r[1]);
    float gg = tanh_f(z2[2] + b2r[2]), og = sigm(z2[3] + b2r[3]);
    c2 = fg * c2 + ig * gg;
    float h = og * tanh_f(c2);
    outy[(size_t)b * 131072 + (size_t)127 * 1024 + j] = h;
    hT2[b * 1024 + j] = h;
    cT2[b * 1024 + j] = c2;
  }
}

// ---------------- launch ----------------
extern "C" void kernel_launch(void* const* d_in, const int* in_sizes, int n_in,
                              void* d_out, int out_size, void* d_ws, size_t ws_size,
                              hipStream_t stream) {
  const int*   x    = (const int*)d_in[0];
  const float* h0_1 = (const float*)d_in[1];
  const float* c0_1 = (const float*)d_in[2];
  const float* h0_2 = (const float*)d_in[3];
  const float* c0_2 = (const float*)d_in[4];
  const float* emb  = (const float*)d_in[5];
  const float* W1   = (const float*)d_in[6];
  const float* U1   = (const float*)d_in[7];
  const float* b1   = (const float*)d_in[8];
  const float* W2   = (const float*)d_in[9];
  const float* U2   = (const float*)d_in[10];
  const float* b2   = (const float*)d_in[11];
  float* outf = (float*)d_out;

  unsigned short* ws  = (unsigned short*)d_ws;
  unsigned short* ebf = ws;                    //  2,097,152 ush
  unsigned short* W1t = ws +  2097152;         //  1,048,576
  unsigned short* U1t = ws +  3145728;         //  4,194,304
  unsigned short* W2t = ws +  7340032;         //  4,194,304
  unsigned short* U2t = ws + 11534336;         //  4,194,304
  unsigned short* h1h = ws + 15728640;         //  8,454,144
  unsigned short* h2h = ws + 24182784;         //  8,454,144
  unsigned int*   bar = (unsigned int*)(ws + 32636928);  // 4 KB (total ~65.3 MB)

  float* hT1 = outf + 8388608;
  float* cT1 = outf + 8454144;
  float* hT2 = outf + 8519680;
  float* cT2 = outf + 8585216;

  zero_bar<<<4, 256, 0, stream>>>(bar);
  prep_e<<<1024, 256, 0, stream>>>(x, emb, ebf);
  prep_wt<<<512,  256, 0, stream>>>(W1, W1t, 256);
  prep_wt<<<2048, 256, 0, stream>>>(U1, U1t, 1024);
  prep_wt<<<2048, 256, 0, stream>>>(W2, W2t, 1024);
  prep_wt<<<2048, 256, 0, stream>>>(U2, U2t, 1024);
  prep_cvt<<<256, 256, 0, stream>>>(h0_1, h1h);
  prep_cvt<<<256, 256, 0, stream>>>(h0_2, h2h);

  // allow 104 KB dynamic LDS (gfx950 has 160 KB/CU)
  static bool attr_done = false;
  if (!attr_done) {
    (void)hipFuncSetAttribute((const void*)lstm_fused,
                              hipFuncAttributeMaxDynamicSharedMemorySize, 106496);
    attr_done = true;
  }

  {
    const unsigned short *w1c = W1t, *u1c = U1t, *w2c = W2t, *u2c = U2t, *ec = ebf;
    unsigned short *h1c = h1h, *h2c = h2h;
    const float *c01 = c0_1, *c02 = c0_2, *b1c = b1, *b2c = b2;
    float *oy = outf, *ht1 = hT1, *ct1 = cT1, *ht2 = hT2, *ct2 = cT2;
    unsigned int* brc = bar;
    void* args[] = {&w1c, &u1c, &w2c, &u2c, &ec, &h1c, &h2c,
                    &c01, &c02, &b1c, &b2c, &oy, &ht1, &ct1, &ht2, &ct2, &brc};
    hipLaunchCooperativeKernel((void*)lstm_fused, dim3(256), dim3(256), args, 106496, stream);
  }
}